// Round 2
// baseline (11260.269 us; speedup 1.0000x reference)
//
#include <hip/hip_runtime.h>
#include <math.h>

#define DD 512
#define SS 1024
#define BB 2
#define HH 8
#define LL 8
#define FF 2048
#define VV 32000
#define ROWS 2048            // B*S
#define NTOT 65536000u       // B*S*V

// ---------------------------------------------------------------- embedding
__global__ __launch_bounds__(256) void embed_kernel(
    const int* __restrict__ ids, const float* __restrict__ emb,
    const float* __restrict__ pos, float* __restrict__ x)
{
    unsigned idx = blockIdx.x * 256u + threadIdx.x;        // ROWS*DD
    unsigned row = idx >> 9, d = idx & 511u;
    unsigned s = row & (SS - 1);
    x[idx] = emb[(size_t)ids[row] * DD + d] + pos[(size_t)s * DD + d];
}

// ---------------------------------------------------------------- rope tables
__global__ __launch_bounds__(256) void rope_table_kernel(float* __restrict__ ctab,
                                                         float* __restrict__ stab)
{
    unsigned idx = blockIdx.x * 256u + threadIdx.x;        // SS*32
    unsigned j = idx & 31u, s = idx >> 5;
    float invf = (float)(1.0 / pow(10000.0, (double)(2 * j) / 64.0));
    float f = (float)s * invf;                              // fp32 mult, like np
    ctab[idx] = (float)cos((double)f);
    stab[idx] = (float)sin((double)f);
}

// ---------------------------------------------------------------- rope + elu+1
__device__ __forceinline__ float elu1(float x) {
    return x > 0.f ? x + 1.f : expm1f(x) + 1.f;
}

__global__ __launch_bounds__(256) void rope_feat_kernel(
    float* __restrict__ q, float* __restrict__ k,
    const float* __restrict__ ctab, const float* __restrict__ stab,
    const float* __restrict__ mask)
{
    unsigned idx = blockIdx.x * 256u + threadIdx.x;        // ROWS*HH*32
    unsigned j = idx & 31u;
    unsigned h = (idx >> 5) & 7u;
    unsigned row = idx >> 8;
    unsigned s = row & (SS - 1);
    float c = ctab[s * 32 + j], sn = stab[s * 32 + j];
    size_t o = (size_t)row * DD + h * 64 + j;
    float q1 = q[o], q2 = q[o + 32];
    float qa = q1 * c - q2 * sn;   // d<32: rot = -q[d+32]
    float qb = q2 * c + q1 * sn;   // d>=32: rot = q[d-32]
    q[o]      = elu1(qa);
    q[o + 32] = elu1(qb);
    float m = mask[row];
    float k1 = k[o], k2 = k[o + 32];
    float ka = k1 * c - k2 * sn;
    float kb = k2 * c + k1 * sn;
    k[o]      = elu1(ka) * m;
    k[o + 32] = elu1(kb) * m;
}

// ---------------------------------------------------------------- linear-attn scan
// one block per (b,h); 256 threads: thread t -> e = t&63, d-range [(t>>6)*16, +16)
__global__ __launch_bounds__(256) void attn_scan_kernel(
    const float* __restrict__ q, const float* __restrict__ k,
    const float* __restrict__ v, float* __restrict__ a)
{
    int bh = blockIdx.x;
    int b = bh >> 3, h = bh & 7;
    int t = threadIdx.x;
    int e = t & 63, dg = t >> 6, d0 = dg << 4;
    size_t base = (size_t)b * SS * DD + h * 64;
    float Sacc[16];
#pragma unroll
    for (int j = 0; j < 16; ++j) Sacc[j] = 0.f;
    float zreg = 0.f;                                   // wave 0: z[t]
    __shared__ float kk[64], vv[64], qq[64];
    __shared__ float pnum[4][64];
    __shared__ float den_sh;
    for (int s = 0; s < SS; ++s) {
        size_t off = base + (size_t)s * DD;
        if (t < 64) kk[t] = k[off + t];
        else if (t < 128) vv[t - 64] = v[off + t - 64];
        else if (t < 192) qq[t - 128] = q[off + t - 128];
        __syncthreads();
        float vval = vv[e];
        float p = 0.f;
#pragma unroll
        for (int j = 0; j < 16; ++j) {
            Sacc[j] += kk[d0 + j] * vval;     // S[d][e] += k[d]*v[e]
            p += qq[d0 + j] * Sacc[j];        // num[e] partial
        }
        pnum[dg][e] = p;
        if (t < 64) {
            zreg += kk[t];
            float pd = qq[t] * zreg;
#pragma unroll
            for (int o = 32; o; o >>= 1) pd += __shfl_down(pd, o);
            if (t == 0) den_sh = pd + 1e-6f;
        }
        __syncthreads();
        if (t < 64) {
            float num = ((pnum[0][t] + pnum[1][t]) + pnum[2][t]) + pnum[3][t];
            a[off + t] = num / den_sh;
        }
        __syncthreads();
    }
}

// ---------------------------------------------------------------- generic SGEMM
// C[M,N] = A[M,K] @ B[K,N] + bias (+ res) (+ gelu). 64x64 tile, K-tile 16.
__global__ __launch_bounds__(256) void gemm_kernel(
    const float* __restrict__ A, const float* __restrict__ B,
    const float* __restrict__ bias, const float* __restrict__ res,
    float* __restrict__ C, int M, int N, int K, int act)
{
    __shared__ float As[16][68];
    __shared__ float Bs[16][68];
    const int t = threadIdx.x;
    const int bn = blockIdx.x, bm = blockIdx.y;
    const int m0 = bm * 64, n0 = bn * 64;
    const int tx = t & 15, ty = t >> 4;
    const int ar = t >> 2, ac = (t & 3) << 2;
    const int br = t >> 4, bc = (t & 15) << 2;
    float acc[4][4] = {};
    for (int k0 = 0; k0 < K; k0 += 16) {
        float4 av = *(const float4*)(A + (size_t)(m0 + ar) * K + (k0 + ac));
        float4 bv = *(const float4*)(B + (size_t)(k0 + br) * N + (n0 + bc));
        As[ac + 0][ar] = av.x; As[ac + 1][ar] = av.y;
        As[ac + 2][ar] = av.z; As[ac + 3][ar] = av.w;
        *(float4*)&Bs[br][bc] = bv;
        __syncthreads();
#pragma unroll
        for (int kkk = 0; kkk < 16; ++kkk) {
            float4 a4 = *(const float4*)&As[kkk][ty << 2];
            float4 b4 = *(const float4*)&Bs[kkk][tx << 2];
            float aa[4] = {a4.x, a4.y, a4.z, a4.w};
            float bb4[4] = {b4.x, b4.y, b4.z, b4.w};
#pragma unroll
            for (int i = 0; i < 4; ++i)
#pragma unroll
                for (int jj = 0; jj < 4; ++jj)
                    acc[i][jj] += aa[i] * bb4[jj];
        }
        __syncthreads();
    }
#pragma unroll
    for (int i = 0; i < 4; ++i) {
        int m = m0 + (ty << 2) + i;
        size_t rowoff = (size_t)m * N + n0 + (tx << 2);
        float tmp[4];
#pragma unroll
        for (int jj = 0; jj < 4; ++jj) {
            int n = n0 + (tx << 2) + jj;
            float vv = acc[i][jj] + bias[n];
            if (res) vv += res[rowoff + jj];
            if (act == 1) {
                float x3 = vv * vv * vv;
                vv = vv * (0.5f * (1.0f + tanhf(0.7978845608028654f * (vv + 0.044715f * x3))));
            }
            tmp[jj] = vv;
        }
        float4 o4 = {tmp[0], tmp[1], tmp[2], tmp[3]};
        *(float4*)(C + rowoff) = o4;
    }
}

// ---------------------------------------------------------------- cond layernorm
__global__ __launch_bounds__(256) void ln_kernel(
    const float* __restrict__ in, float* __restrict__ out,
    const float* __restrict__ g, const float* __restrict__ b,
    const int* __restrict__ cond)
{
    int row = blockIdx.x;
    int c = cond[row >> 10];
    const float* xr = in + (size_t)row * DD;
    int t = threadIdx.x;
    float v0 = xr[t], v1 = xr[t + 256];
    __shared__ float sm[8];
    int lane = t & 63, w = t >> 6;
    float s1 = v0 + v1;
#pragma unroll
    for (int o = 32; o; o >>= 1) s1 += __shfl_down(s1, o);
    if (lane == 0) sm[w] = s1;
    __syncthreads();
    if (t == 0) sm[0] = sm[0] + sm[1] + sm[2] + sm[3];
    __syncthreads();
    float mu = sm[0] * (1.0f / 512.0f);
    __syncthreads();
    float d0 = v0 - mu, d1 = v1 - mu;
    float s2 = d0 * d0 + d1 * d1;
#pragma unroll
    for (int o = 32; o; o >>= 1) s2 += __shfl_down(s2, o);
    if (lane == 0) sm[w] = s2;
    __syncthreads();
    if (t == 0) sm[0] = sm[0] + sm[1] + sm[2] + sm[3];
    __syncthreads();
    float var = sm[0] * (1.0f / 512.0f);
    float sd = sqrtf(var + 1e-5f);
    const float* gr = g + (size_t)c * DD;
    const float* br = b + (size_t)c * DD;
    out[(size_t)row * DD + t]       = (d0 / sd) * gr[t] + br[t];
    out[(size_t)row * DD + t + 256] = (d1 / sd) * gr[t + 256] + br[t + 256];
}

// ---------------------------------------------------------------- threefry gumbel
// Modern JAX (>=0.4.36) defaults jax_threefry_partitionable=True:
// per-element uint64 counter i -> threefry2x32(key, (hi(i), lo(i))),
// 32-bit output = bits1 ^ bits2. Here size < 2^32 so hi(i)==0.
__device__ __forceinline__ unsigned rotl32(unsigned x, int r) {
    return (x << r) | (x >> (32 - r));
}

__device__ __forceinline__ float gumbel_noise(unsigned i)
{
    const unsigned k0 = 0u, k1 = 42u, k2 = 0x1BD11BDAu ^ 0u ^ 42u;
    unsigned x0 = 0u;     // counts_hi
    unsigned x1 = i;      // counts_lo
#define TFR(r) { x0 += x1; x1 = rotl32(x1, r); x1 ^= x0; }
    x0 += k0; x1 += k1;
    TFR(13) TFR(15) TFR(26) TFR(6)
    x0 += k1; x1 += k2 + 1u;
    TFR(17) TFR(29) TFR(16) TFR(24)
    x0 += k2; x1 += k0 + 2u;
    TFR(13) TFR(15) TFR(26) TFR(6)
    x0 += k0; x1 += k1 + 3u;
    TFR(17) TFR(29) TFR(16) TFR(24)
    x0 += k1; x1 += k2 + 4u;
    TFR(13) TFR(15) TFR(26) TFR(6)
    x0 += k2; x1 += k0 + 5u;
#undef TFR
    unsigned bits = x0 ^ x1;
    float u = __uint_as_float((bits >> 9) | 0x3f800000u) - 1.0f;
    float uu = u > 0.f ? u : 1.175494350822288e-38f;   // max(tiny, u) — matches jax uniform
    return -logf(-logf(uu));
}

__global__ __launch_bounds__(256) void gumbel_argmax_kernel(
    const float* __restrict__ logits, float* __restrict__ out1)
{
    int row = blockIdx.x;
    unsigned base = (unsigned)row * VV;
    int t = threadIdx.x;
    float best = -3.4e38f;
    int bi = VV;
    for (int v = t; v < VV; v += 256) {
        float val = logits[base + v] + gumbel_noise(base + v);
        if (val > best) { best = val; bi = v; }   // keeps first occurrence
    }
    __shared__ float bv[256];
    __shared__ int bix[256];
    bv[t] = best; bix[t] = bi;
    __syncthreads();
    for (int off = 128; off; off >>= 1) {
        if (t < off) {
            float ov = bv[t + off]; int oi = bix[t + off];
            if (ov > bv[t] || (ov == bv[t] && oi < bix[t])) { bv[t] = ov; bix[t] = oi; }
        }
        __syncthreads();
    }
    int amax = bix[0];
    for (int v = t; v < VV; v += 256)
        out1[base + v] = (v == amax) ? 1.0f : 0.0f;
}

// ---------------------------------------------------------------- launch
extern "C" void kernel_launch(void* const* d_in, const int* in_sizes, int n_in,
                              void* d_out, int out_size, void* d_ws, size_t ws_size,
                              hipStream_t stream)
{
    const int*   ids   = (const int*)  d_in[0];
    const int*   cond  = (const int*)  d_in[1];
    const float* mask  = (const float*)d_in[2];
    // d_in[3] = inverse_temperature (==1, cancels in argmax) — unused
    const float* emb   = (const float*)d_in[4];
    const float* pos   = (const float*)d_in[5];
    const float* Wq    = (const float*)d_in[6];
    const float* bq    = (const float*)d_in[7];
    const float* Wk    = (const float*)d_in[8];
    const float* bk    = (const float*)d_in[9];
    const float* Wv    = (const float*)d_in[10];
    const float* bv    = (const float*)d_in[11];
    const float* Wo    = (const float*)d_in[12];
    const float* bo    = (const float*)d_in[13];
    const float* W1    = (const float*)d_in[14];
    const float* b1    = (const float*)d_in[15];
    const float* W2    = (const float*)d_in[16];
    const float* b2    = (const float*)d_in[17];
    const float* cn1g  = (const float*)d_in[18];
    const float* cn1b  = (const float*)d_in[19];
    const float* cn2g  = (const float*)d_in[20];
    const float* cn2b  = (const float*)d_in[21];
    const float* ng    = (const float*)d_in[22];
    const float* nb    = (const float*)d_in[23];
    const float* Wout  = (const float*)d_in[24];
    const float* bout  = (const float*)d_in[25];

    float* out0 = (float*)d_out;
    float* out1 = out0 + (size_t)NTOT;

    const size_t NX = (size_t)ROWS * DD;     // 1,048,576
    float* ws   = (float*)d_ws;
    float* x    = ws;
    float* xr   = x + NX;
    float* qb   = xr + NX;
    float* kb   = qb + NX;
    float* vb2  = kb + NX;
    float* ab   = vb2 + NX;
    float* h1   = ab + NX;                   // ROWS*FF = 4,194,304
    float* ctab = h1 + (size_t)ROWS * FF;
    float* stab = ctab + SS * 32;

    embed_kernel<<<(ROWS * DD) / 256, 256, 0, stream>>>(ids, emb, pos, x);
    rope_table_kernel<<<(SS * 32) / 256, 256, 0, stream>>>(ctab, stab);

    for (int l = 0; l < LL; ++l) {
        const float* wq = Wq + (size_t)l * DD * DD;
        const float* wk = Wk + (size_t)l * DD * DD;
        const float* wv = Wv + (size_t)l * DD * DD;
        const float* wo = Wo + (size_t)l * DD * DD;
        const float* w1 = W1 + (size_t)l * DD * FF;
        const float* w2 = W2 + (size_t)l * FF * DD;

        dim3 g512(DD / 64, ROWS / 64);
        gemm_kernel<<<g512, 256, 0, stream>>>(x, wq, bq + l * DD, nullptr, qb, ROWS, DD, DD, 0);
        gemm_kernel<<<g512, 256, 0, stream>>>(x, wk, bk + l * DD, nullptr, kb, ROWS, DD, DD, 0);
        gemm_kernel<<<g512, 256, 0, stream>>>(x, wv, bv + l * DD, nullptr, vb2, ROWS, DD, DD, 0);

        rope_feat_kernel<<<(ROWS * HH * 32) / 256, 256, 0, stream>>>(qb, kb, ctab, stab, mask);
        attn_scan_kernel<<<BB * HH, 256, 0, stream>>>(qb, kb, vb2, ab);

        gemm_kernel<<<g512, 256, 0, stream>>>(ab, wo, bo + l * DD, x, xr, ROWS, DD, DD, 0);
        ln_kernel<<<ROWS, 256, 0, stream>>>(xr, x, cn1g + (size_t)l * 4 * DD, cn1b + (size_t)l * 4 * DD, cond);

        dim3 gF(FF / 64, ROWS / 64);
        gemm_kernel<<<gF, 256, 0, stream>>>(x, w1, b1 + l * FF, nullptr, h1, ROWS, FF, DD, 1);
        gemm_kernel<<<g512, 256, 0, stream>>>(h1, w2, b2 + l * DD, x, xr, ROWS, DD, FF, 0);
        ln_kernel<<<ROWS, 256, 0, stream>>>(xr, x, cn2g + (size_t)l * 4 * DD, cn2b + (size_t)l * 4 * DD, cond);
    }

    ln_kernel<<<ROWS, 256, 0, stream>>>(x, xr, ng, nb, cond);

    dim3 gV(VV / 64, ROWS / 64);
    gemm_kernel<<<gV, 256, 0, stream>>>(xr, Wout, bout, nullptr, out0, ROWS, VV, DD, 0);

    gumbel_argmax_kernel<<<ROWS, 256, 0, stream>>>(out0, out1);
}